// Round 8
// baseline (157.755 us; speedup 1.0000x reference)
//
#include <hip/hip_runtime.h>

// BackgroundNoiseLayer, round 8: split homogeneous pipeline.
//   out[t, n*5+r] = sum_k spikes[t,k] * W[k, n*5+r],
//   W[k, c] = scatter-add over edges e (cols[e]=k, rows[e]=n) of weights[e]*tau[e,r]
//
// memset: zero bin counters
// K1 : bucket edges (bin = row/16, 16 B records {key, 5 bf16 w*tau});
//      also builds the fragment-ordered bf16 spike table spbf[nt][kk][lane].
// K2a: per bin: zero f32 LDS slice -> LDS atomic scatter -> convert to bf16
//      fragments written COALESCED to global Wg, fragment-interleaved
//      [bin][kk][m][lane] (1 KB per (kk,m) chunk).
// K2b: pure streaming MFMA GEMM, no LDS, no barriers: A-frags from Wg
//      (coalesced 16 B/lane), B-frags from spbf (L1/L2-hot), float4 stores.
//      Traffic = 64 MB read + 244 MB write -> ~49 us floor.

#define N_NEURONS 50000
#define N_BKG     100
#define N_SYN     5
#define N_EDGES   500000
#define SEQ_T     250
#define NCOL      (N_NEURONS * N_SYN)   // 250000
#define RPB       16                    // neurons per bin
#define NBINS     (N_NEURONS / RPB)     // 3125
#define CAP       512                   // record cap per bin (mean 160, +28 sigma)
#define KPAD      128                   // K padded 100 -> 128
#define CPAD      81                    // f32 slice leading dim
#define BCOLS     80                    // output cols per bin

// d_ws layout
#define WS_COUNT_OFF 0                          // NBINS u32
#define WS_SPB_OFF   32768                      // 4096 * 16 B = 64 KB
#define WS_REC_OFF   131072                     // NBINS*CAP*16 B = 25.6 MB
#define WS_WG_OFF    (131072 + (size_t)NBINS * CAP * 16)   // 64.0 MB Wg

typedef __attribute__((ext_vector_type(8))) short bf16x8;
typedef __attribute__((ext_vector_type(4))) float f32x4;

__device__ inline unsigned short bf16_rne(float f) {
    unsigned u = __builtin_bit_cast(unsigned, f);
    u += 0x7FFFu + ((u >> 16) & 1u);
    return (unsigned short)(u >> 16);
}
__device__ inline float bf16_up(unsigned hw) {
    return __builtin_bit_cast(float, hw << 16);
}

// K1: bucket-append edges; gids < 4096 also build the fragment-ordered
// spike table: unit gid = (nt*4 + kk)*64 + lane, value[i] =
// bf16(spikes[t, k0+i]), t = nt*16+(lane&15), k0 = kk*32+(lane>>4)*8.
__global__ __launch_bounds__(256) void bucket_kernel(
        const float* __restrict__ weights,
        const float* __restrict__ tau,
        const int*   __restrict__ rows,
        const int*   __restrict__ cols,
        const float* __restrict__ spikes,
        unsigned* __restrict__ count,
        uint4* __restrict__ rec,
        bf16x8* __restrict__ spbf) {
    int gid = blockIdx.x * 256 + threadIdx.x;
    if (gid < 4096) {
        int lane = gid & 63;
        int kk   = (gid >> 6) & 3;
        int nt   = gid >> 8;
        int t    = nt * 16 + (lane & 15);
        int k0   = kk * 32 + (lane >> 4) * 8;
        bf16x8 v;
#pragma unroll
        for (int i = 0; i < 8; ++i) {
            float s = 0.f;
            if (t < SEQ_T && (k0 + i) < N_BKG)
                s = spikes[t * N_BKG + k0 + i];      // 0/1 -> bf16 exact
            v[i] = (short)bf16_rne(s);
        }
        spbf[gid] = v;
    }
    if (gid >= N_EDGES) return;
    int row = rows[gid];
    int col = cols[gid];
    float w = weights[gid];
    const float* tp = tau + (size_t)gid * N_SYN;
    int bin = row >> 4;
    unsigned slot = atomicAdd(&count[bin], 1u);
    if (slot >= CAP) return;                     // statistically impossible
    uint4 r;
    r.x = ((unsigned)col << 4) | (unsigned)(row & 15);
    r.y = (unsigned)bf16_rne(w * tp[0]) | ((unsigned)bf16_rne(w * tp[1]) << 16);
    r.z = (unsigned)bf16_rne(w * tp[2]) | ((unsigned)bf16_rne(w * tp[3]) << 16);
    r.w = (unsigned)bf16_rne(w * tp[4]);
    rec[(size_t)bin * CAP + slot] = r;
}

// K2a: per-bin scatter + convert. 3125 blocks x 256 (4 blocks/CU, 32.4 KB LDS).
__global__ __launch_bounds__(256, 4) void scatter_kernel(
        const unsigned* __restrict__ count,
        const uint4* __restrict__ rec,
        bf16x8* __restrict__ wg) {
    __shared__ float slice[N_BKG * CPAD];        // 100 x 81 f32 = 32.4 KB

    const int tid = threadIdx.x;
    const int b   = blockIdx.x;

    // unguarded preloads: count and both records issue in parallel
    unsigned cnt = count[b];
    uint4 ra = rec[(size_t)b * CAP + tid];
    uint4 rb = rec[(size_t)b * CAP + tid + 256];
    if (cnt > CAP) cnt = CAP;

    // zero slice (8100 f32 = 2025 f32x4)
    {
        f32x4* s4 = (f32x4*)slice;
        f32x4 z = (f32x4){0.f, 0.f, 0.f, 0.f};
#pragma unroll
        for (int j = 0; j < 8; ++j) {
            int i = tid + j * 256;
            if (i < 2025) s4[i] = z;
        }
    }
    __syncthreads();

    // LDS f32 atomic scatter
    if ((unsigned)tid < cnt) {
        float* base = &slice[(ra.x >> 4) * CPAD + (ra.x & 15u) * N_SYN];
        atomicAdd(base + 0, bf16_up(ra.y & 0xFFFFu));
        atomicAdd(base + 1, bf16_up(ra.y >> 16));
        atomicAdd(base + 2, bf16_up(ra.z & 0xFFFFu));
        atomicAdd(base + 3, bf16_up(ra.z >> 16));
        atomicAdd(base + 4, bf16_up(ra.w & 0xFFFFu));
    }
    if ((unsigned)tid + 256u < cnt) {
        float* base = &slice[(rb.x >> 4) * CPAD + (rb.x & 15u) * N_SYN];
        atomicAdd(base + 0, bf16_up(rb.y & 0xFFFFu));
        atomicAdd(base + 1, bf16_up(rb.y >> 16));
        atomicAdd(base + 2, bf16_up(rb.z & 0xFFFFu));
        atomicAdd(base + 3, bf16_up(rb.z >> 16));
        atomicAdd(base + 4, bf16_up(rb.w & 0xFFFFu));
    }
    __syncthreads();

    // convert + coalesced global write: 1280 units = 20 chunks x 64 lanes
    bf16x8* wgb = wg + (size_t)b * 1280;
#pragma unroll
    for (int j = 0; j < 5; ++j) {
        int u    = j * 256 + tid;                // 0..1279
        int kk   = u / 320;
        int rem  = u - kk * 320;
        int m    = rem >> 6;
        int lane = rem & 63;
        int c    = m * 16 + (lane & 15);
        int k0   = kk * 32 + (lane >> 4) * 8;
        bf16x8 v;
#pragma unroll
        for (int i = 0; i < 8; ++i) {
            float f = (k0 + i < N_BKG) ? slice[(k0 + i) * CPAD + c] : 0.f;
            v[i] = (short)bf16_rne(f);
        }
        wgb[(kk * 5 + m) * 64 + lane] = v;
    }
}

// K2b: pure streaming MFMA GEMM. 3125 blocks x 256 (4 waves), no LDS/barriers.
// Swapped operands: A = W frag (M = c), B = spike frag (N = t).
// D: col = t = l&15, row = c = (l>>4)*4+reg -> float4 stores along c
// (mapping verified rounds 5-7).
__global__ __launch_bounds__(256, 4) void gemm_kernel(
        const bf16x8* __restrict__ wg,
        const bf16x8* __restrict__ spbf,
        float* __restrict__ out) {
    const int tid = threadIdx.x;
    const int b   = blockIdx.x;
    const int l  = tid & 63;
    const int wv = tid >> 6;
    const int lc = l & 15;
    const int lq = l >> 4;

    const bf16x8* wgb = wg + (size_t)b * 1280;

    f32x4 acc[5][4];
#pragma unroll
    for (int m = 0; m < 5; ++m)
#pragma unroll
        for (int n = 0; n < 4; ++n)
            acc[m][n] = (f32x4){0.f, 0.f, 0.f, 0.f};

#pragma unroll
    for (int kk = 0; kk < 4; ++kk) {
        bf16x8 bs[4];
#pragma unroll
        for (int n = 0; n < 4; ++n) {
            int nt = wv * 4 + n;
            bs[n] = spbf[(nt * 4 + kk) * 64 + l];
        }
#pragma unroll
        for (int m = 0; m < 5; ++m) {
            bf16x8 ah = wgb[(kk * 5 + m) * 64 + l];
#pragma unroll
            for (int n = 0; n < 4; ++n)
                acc[m][n] = __builtin_amdgcn_mfma_f32_16x16x32_bf16(
                                ah, bs[n], acc[m][n], 0, 0, 0);
        }
    }

    const int cb = b * BCOLS;
#pragma unroll
    for (int m = 0; m < 5; ++m) {
        int c = cb + m * 16 + lq * 4;
#pragma unroll
        for (int n = 0; n < 4; ++n) {
            int t = (wv * 4 + n) * 16 + lc;
            if (t < SEQ_T)
                *(f32x4*)(out + (size_t)t * NCOL + c) = acc[m][n];
        }
    }
}

extern "C" void kernel_launch(void* const* d_in, const int* in_sizes, int n_in,
                              void* d_out, int out_size, void* d_ws, size_t ws_size,
                              hipStream_t stream) {
    const float* weights = (const float*)d_in[0];
    const float* tau     = (const float*)d_in[1];
    const float* spikes  = (const float*)d_in[2];
    const int*   rows    = (const int*)d_in[3];
    const int*   cols    = (const int*)d_in[4];
    float* out = (float*)d_out;

    char* ws = (char*)d_ws;
    unsigned* count = (unsigned*)(ws + WS_COUNT_OFF);
    bf16x8*   spbf  = (bf16x8*)(ws + WS_SPB_OFF);
    uint4*    rec   = (uint4*)(ws + WS_REC_OFF);
    bf16x8*   wg    = (bf16x8*)(ws + WS_WG_OFF);

    hipMemsetAsync(count, 0, NBINS * sizeof(unsigned), stream);

    int eblocks = (N_EDGES + 255) / 256;
    bucket_kernel<<<eblocks, 256, 0, stream>>>(weights, tau, rows, cols, spikes,
                                               count, rec, spbf);

    scatter_kernel<<<NBINS, 256, 0, stream>>>(count, rec, wg);

    gemm_kernel<<<NBINS, 256, 0, stream>>>(wg, spbf, out);
}